// Round 10
// baseline (419.510 us; speedup 1.0000x reference)
//
#include <hip/hip_runtime.h>

typedef unsigned short u16;
typedef unsigned int   u32;
typedef unsigned long long u64;
typedef __attribute__((ext_vector_type(8))) short bf16x8;
typedef __attribute__((ext_vector_type(4))) float f32x4;

#define DEV static __device__ __forceinline__

DEV u16 f2bf(float f){ union{float f; u32 i;} v; v.f=f; u32 u=v.i;
                       return (u16)((u + 0x7FFFu + ((u>>16)&1u))>>16); }
DEV float bf2f(u16 u){ union{u32 i; float f;} v; v.i=((u32)u)<<16; return v.f; }
DEV float bfl(u32 w){ return bf2f((u16)(w & 0xffffu)); }
DEV float bfh(u32 w){ return bf2f((u16)(w >> 16)); }
DEV u32 pk2(float a, float b){ return (u32)f2bf(a) | ((u32)f2bf(b) << 16); }
// LOAD-BEARING (R12 post-mortem): LDS stores are u16, reads are u32 — without the
// "memory" clobber the compiler's alias analysis reorders them (absmax=inf).
DEV void ldsfence(){ asm volatile("s_waitcnt lgkmcnt(0)" ::: "memory"); }
// R9 (verified): compiler-ordering barrier WITHOUT the hardware drain. Per-warp-private
// LDS + CDNA per-wave in-order DS pipe => intra-wave RAW/WAR satisfied by program
// order; compiler inserts counted lgkmcnt at first consumer. absmax held in R9.
DEV void ldsorder(){ asm volatile("" ::: "memory"); }

// ---- bias slab (f32): bin,bp1,bp2,b_att1(fused),ba2,bout ----
#define NBIAS 384
// ---- fragment buffer FB: [frag][lane][8] u16 ----
#define FB_P1 0
#define FB_P2 4
#define FB_A1 12   // fused Wp2@Wa1
#define FB_A2 20
#define FB_IN 28
#define FB_LIN 36
#define FB_SRC 44  // fused Wsrc@Wa1
#define FB_DST 52  // fused Wdst@Wa1
#define FB_OUT 60
#define NFRAG 68

// LDS row stride: 70 u16 = 35 dwords -> fragment reads ~2-way bank alias (free, m136).
#define LROW 70
#define LROWD 35

DEV bf16x8 fb_load(const u16* __restrict__ FB, int frag, int lane){
  union{ uint4 u; bf16x8 v; } w;
  w.u = *(const uint4*)(FB + ((size_t)(frag*64+lane))*8);
  return w.v;
}
DEV bf16x8 lds_read_chunk(const u32* l32, int dw){
  union{ u32 d[4]; bf16x8 v; } u;
#pragma unroll
  for(int p=0;p<4;p++) u.d[p] = l32[dw+p];
  return u.v;
}

// ---------- prep: bias slab + fragment buffer + degree histogram (merged) ----------
#define PREP_BLOCKS 19
__global__ __launch_bounds__(256) void k_prep(
  const float* __restrict__ Win, const float* __restrict__ Wlin,
  const float* __restrict__ Wsrc, const float* __restrict__ Wdst,
  const float* __restrict__ Wp1, const float* __restrict__ Wp2,
  const float* __restrict__ Wa1, const float* __restrict__ Wa2,
  const float* __restrict__ Wout,
  const float* __restrict__ bin, const float* __restrict__ bp1, const float* __restrict__ bp2,
  const float* __restrict__ ba1, const float* __restrict__ ba2, const float* __restrict__ bout,
  float* __restrict__ Bf, u16* __restrict__ FB,
  const int* __restrict__ ei, int* __restrict__ deg, int E)
{
  if(blockIdx.x >= PREP_BLOCKS){
    int e = (blockIdx.x - PREP_BLOCKS)*256 + threadIdx.x;
    if(e < E) atomicAdd(&deg[ei[(size_t)E + e]], 1);
    return;
  }
  int idx = blockIdx.x*256 + threadIdx.x;
  if(idx < NBIAS){
    int which = idx >> 6, c = idx & 63;
    if(which == 3){                         // fused attn-L1 bias: bp2@Wa1 + ba1
      float sacc = ba1[c];
      for(int k=0;k<64;k++) sacc += bp2[k]*Wa1[k*64+c];
      Bf[idx] = sacc;
    } else {
      const float* b;
      switch(which){ case 0:b=bin;break; case 1:b=bp1;break; case 2:b=bp2;break;
                     case 4:b=ba2;break; default:b=bout;break; }
      Bf[idx] = b[c];
    }
  } else if(idx < NBIAS + NFRAG*64){
    int j = idx - NBIAS;
    int frag = j >> 6, lane = j & 63;
    int t = lane & 15, q = lane >> 4;
    const float* src = nullptr; const float* fuse = nullptr;
    int K = 64, nt, s;
    if(frag < 4){ src = Wp1; K = 3; nt = frag; s = 0; }
    else if(frag < 12){ int g=frag-4;  src=Wp2;  nt=g>>1; s=g&1; }
    else if(frag < 20){ int g=frag-12; fuse=Wp2; nt=g>>1; s=g&1; }   // Wp2@Wa1
    else if(frag < 28){ int g=frag-20; src=Wa2;  nt=g>>1; s=g&1; }
    else if(frag < 36){ int g=frag-28; src=Win;  nt=g>>1; s=g&1; }
    else if(frag < 44){ int g=frag-36; src=Wlin; nt=g>>1; s=g&1; }
    else if(frag < 52){ int g=frag-44; fuse=Wsrc; nt=g>>1; s=g&1; }  // Wsrc@Wa1
    else if(frag < 60){ int g=frag-52; fuse=Wdst; nt=g>>1; s=g&1; }  // Wdst@Wa1
    else              { int g=frag-60; src=Wout; nt=g>>1; s=g&1; }
    u16* dst = FB + ((size_t)(frag*64+lane))*8;
    if(fuse){
      int col = nt*16 + t;
#pragma unroll
      for(int jj=0;jj<8;jj++){
        int k = s*32 + q*8 + jj;
        const float* ar = fuse + k*64;
        float accv = 0.f;
        for(int m=0;m<64;m++) accv += ar[m] * Wa1[m*64+col];
        dst[jj] = f2bf(accv);
      }
    } else {
#pragma unroll
      for(int jj=0;jj<8;jj++){
        int k = s*32 + q*8 + jj;
        dst[jj] = (k<K) ? f2bf(src[k*64 + nt*16 + t]) : (u16)0;
      }
    }
  }
}

// ---------- CSR scans ----------
__global__ __launch_bounds__(256) void k_scanA(const int* __restrict__ deg,
    int* __restrict__ row_start, int* __restrict__ bsum, int N){
  __shared__ int b[256];
  int tid = threadIdx.x, i = blockIdx.x*256 + tid;
  int v = (i<N) ? deg[i] : 0;
  b[tid] = v; __syncthreads();
#pragma unroll
  for(int off=1; off<256; off<<=1){
    int u = (tid>=off) ? b[tid-off] : 0;
    __syncthreads(); b[tid] += u; __syncthreads();
  }
  if(i<N) row_start[i] = b[tid] - v;
  if(tid==255) bsum[blockIdx.x] = b[255];
}

__global__ __launch_bounds__(256) void k_scanBC(
  const int* __restrict__ bsum, int* __restrict__ row_start, int nb, int N)
{
  __shared__ int b[256];
  __shared__ int ex[256];
  int tid = threadIdx.x;
  int v = (tid<nb) ? bsum[tid] : 0;
  b[tid] = v; __syncthreads();
#pragma unroll
  for(int off=1; off<256; off<<=1){
    int u = (tid>=off) ? b[tid-off] : 0;
    __syncthreads(); b[tid] += u; __syncthreads();
  }
  ex[tid] = b[tid] - v;        // exclusive prefix
  __syncthreads();
  int off0 = ex[blockIdx.x];
  int i = blockIdx.x*256 + tid;
  if(i<N) row_start[i] += off0;
  if(blockIdx.x==0 && tid==255) row_start[N] = b[255];
}

// ---------- merged mid-stage v2: scatter ∥ node-side MFMA ∥ S/num zero-fill ----------
__global__ __launch_bounds__(256) void k_mid2(
  const int* __restrict__ ei, const int* __restrict__ row_start, int* __restrict__ cursor,
  int2* __restrict__ pair, int E, int sblocks,
  const float* __restrict__ x, const float* __restrict__ Bf, const u16* __restrict__ FB,
  u16* __restrict__ vf, u16* __restrict__ asof, u16* __restrict__ adof,
  int N, int ntiles, int nodeblocks,
  float* __restrict__ Z, int zcount4, int zblocks)
{
  __shared__ u16 sc16[4][16*LROW];
  int bid = blockIdx.x;

  if(bid < sblocks){
    int e = bid*256 + threadIdx.x;
    if(e < E){
      int d = ei[(size_t)E + e];
      int p = atomicAdd(&cursor[d], 1);
      int2 pr; pr.x = ei[e]; pr.y = d;
      pair[row_start[d] + p] = pr;
    }
    return;
  }
  if(bid >= sblocks + nodeblocks){
    int zb = bid - sblocks - nodeblocks;
    float4* Z4 = (float4*)Z;
    float4 z = {0.f,0.f,0.f,0.f};
    for(int i = zb*256 + threadIdx.x; i < zcount4; i += zblocks*256) Z4[i] = z;
    return;
  }

  int lane = threadIdx.x & 63, warp = threadIdx.x >> 6;
  int t = lane & 15, q = lane >> 4;
  int tile = (bid - sblocks)*4 + warp;
  if(tile >= ntiles) return;
  u16* lb = sc16[warp]; u32* lb32 = (u32*)lb;
  int r0 = tile*16;
  int row = r0 + t; if(row >= N) row = N-1;

  const float4* x4 = (const float4*)(x + (size_t)row*64);
  bf16x8 xa[2];
#pragma unroll
  for(int s=0;s<2;s++){
    float4 u0 = x4[s*8 + q*2], u1 = x4[s*8 + q*2 + 1];
    xa[s][0]=(short)f2bf(u0.x); xa[s][1]=(short)f2bf(u0.y);
    xa[s][2]=(short)f2bf(u0.z); xa[s][3]=(short)f2bf(u0.w);
    xa[s][4]=(short)f2bf(u1.x); xa[s][5]=(short)f2bf(u1.y);
    xa[s][6]=(short)f2bf(u1.z); xa[s][7]=(short)f2bf(u1.w);
  }
  f32x4 zero = {0.f,0.f,0.f,0.f};
  f32x4 acc[4];
#pragma unroll
  for(int nt=0;nt<4;nt++){
    acc[nt] = __builtin_amdgcn_mfma_f32_16x16x32_bf16(xa[0], fb_load(FB, FB_IN+nt*2+0, lane), zero, 0,0,0);
    acc[nt] = __builtin_amdgcn_mfma_f32_16x16x32_bf16(xa[1], fb_load(FB, FB_IN+nt*2+1, lane), acc[nt], 0,0,0);
  }
#pragma unroll
  for(int nt=0;nt<4;nt++)
#pragma unroll
    for(int r=0;r<4;r++)
      lb[(q*4+r)*LROW + nt*16 + t] = f2bf(fmaxf(acc[nt][r] + Bf[nt*16+t], 0.f));
  ldsfence();
  bf16x8 h0 = lds_read_chunk(lb32, t*LROWD + q*4);
  bf16x8 h1 = lds_read_chunk(lb32, t*LROWD + 16 + q*4);

  const int fb0[3] = {FB_LIN, FB_SRC, FB_DST};
  u16* Os[3] = {vf, asof, adof};
#pragma unroll
  for(int mtx=0; mtx<3; mtx++){
    f32x4 av[4];
#pragma unroll
    for(int nt=0;nt<4;nt++){
      av[nt] = __builtin_amdgcn_mfma_f32_16x16x32_bf16(h0, fb_load(FB, fb0[mtx]+nt*2+0, lane), zero, 0,0,0);
      av[nt] = __builtin_amdgcn_mfma_f32_16x16x32_bf16(h1, fb_load(FB, fb0[mtx]+nt*2+1, lane), av[nt], 0,0,0);
    }
    u16* O = Os[mtx];
#pragma unroll
    for(int r=0;r<4;r++){
      int rr = r0 + q*4 + r;
      if(rr < N){
        uint2 o;
        o.x = (u32)f2bf(av[0][r]) | ((u32)f2bf(av[1][r]) << 16);
        o.y = (u32)f2bf(av[2][r]) | ((u32)f2bf(av[3][r]) << 16);
        *(uint2*)(O + (size_t)rr*64 + t*4) = o;
      }
    }
  }
}

// ---------- segment flush ----------
DEV void flushseg(int d, float* numP, float* SP, const int* __restrict__ row_start,
                  float* __restrict__ num, float* __restrict__ S,
                  int lo, int hi, int q, int t){
  if(d < 0) return;
#pragma unroll
  for(int nt=0;nt<4;nt++){
    numP[nt] += __shfl_xor(numP[nt], 16, 64);
    numP[nt] += __shfl_xor(numP[nt], 32, 64);
    SP[nt]   += __shfl_xor(SP[nt],   16, 64);
    SP[nt]   += __shfl_xor(SP[nt],   32, 64);
  }
  bool partial = (row_start[d] < lo) || (row_start[d+1] > hi);
  if(q==0){
#pragma unroll
    for(int nt=0;nt<4;nt++){
      size_t off = (size_t)d*64 + nt*16 + t;
      if(partial){ atomicAdd(&num[off], numP[nt]); atomicAdd(&S[off], SP[nt]); }
      else       { num[off] = numP[nt]; S[off] = SP[nt]; }
    }
  }
#pragma unroll
  for(int nt=0;nt<4;nt++){ numP[nt]=0.f; SP[nt]=0.f; }
}

// ---------- segmented accumulate for one 16-edge tile ----------
DEV void agg_tile(int tbase, int hi_w, int lo_w, int did,
                  const float wv[4][4], const float pd[4][4],
                  int& cur_d, float* numP, float* SP,
                  const int* __restrict__ row_start,
                  float* __restrict__ num, float* __restrict__ S, int q, int t){
  int m = 0;
  while(m < 16){
    int d0 = __shfl(did, m, 64);
    u32 same = (u32)(__ballot(did == d0) & 0xFFFFull);
    u32 rest = ~(same >> m);
    int len = __ffs(rest) - 1;
    int m1 = m + len;
    if(d0 != cur_d){
      flushseg(cur_d, numP, SP, row_start, num, S, lo_w, hi_w, q, t);
      cur_d = d0;
    }
#pragma unroll
    for(int r=0;r<4;r++){
      int mm = q*4 + r;
      bool use = (mm >= m) && (mm < m1) && ((tbase+mm) < hi_w);
      if(use){
#pragma unroll
        for(int nt=0;nt<4;nt++){
          numP[nt] += wv[nt][r] * pd[r][nt];
          SP[nt]   += wv[nt][r];
        }
      }
    }
    m = m1;
  }
}

// ---------- packed edge pipeline v10: TRIPLE-chain ----------
// R9 post-mortem: occupancy hard-capped at 2 waves/SIMD (reg map R3-R5); drains
// already removed; ~50% of k_edge cycles are dependency stalls TLP can't cover.
// Remaining lever = ILP: 3 independent 16-edge chains per iteration (48 edges),
// 1.5x independent work in every serialized phase. Per-edge op counts unchanged.
// Reg budget: compiler used only 128/256 at (256,2) -> headroom exists; corr-C
// gather staggered after A1-A to cap the peak (R5 trick). LDS 53.8KB/block
// (2 blocks/CU = 107.5KB < 160KB). SPILL GATE: FETCH ~91MB / WRITE ~26MB.
__global__ __launch_bounds__(256,2) void k_edge_p10(
  const int* __restrict__ row_start, const int2* __restrict__ pair,
  const float* __restrict__ pos, const float* __restrict__ Bf, const u16* __restrict__ FB,
  const u16* __restrict__ vf, const u16* __restrict__ asof, const u16* __restrict__ adof,
  float* __restrict__ S, float* __restrict__ num, int E, int nsuper, int spw)
{
  __shared__ u16 sc16[4][2*48*LROW];   // per-warp: buf0 = r1/at (48 rows), buf1 = u/au
  int lane = threadIdx.x & 63, warp = threadIdx.x >> 6;
  int t = lane & 15, q = lane >> 4;
  int wid = blockIdx.x*4 + warp;
  int s0 = wid*spw, s1 = s0 + spw;
  if(s0 >= nsuper) return;
  if(s1 > nsuper) s1 = nsuper;
  int lo = s0*48, hi = s1*48; if(hi > E) hi = E;
  u16* lb = sc16[warp];             u32* lb32 = (u32*)lb;
  u16* lu = sc16[warp] + 48*LROW;   u32* lu32 = (u32*)lu;

  float bp1f[4], bp2f[4], baf[4], ba2f[4];
#pragma unroll
  for(int nt=0;nt<4;nt++){
    bp1f[nt]=Bf[ 64+nt*16+t]; bp2f[nt]=Bf[128+nt*16+t];
    baf[nt] =Bf[192+nt*16+t]; ba2f[nt]=Bf[256+nt*16+t];   // baf = bp2@Wa1 + ba1 (fused)
  }
  const uint2* ad2 = (const uint2*)adof;   // permuted: [node][t*4+nt]
  const uint2* as2 = (const uint2*)asof;
  const uint2* v2  = (const uint2*)vf;
  f32x4 zero = {0.f,0.f,0.f,0.f};
  float numP[4] = {0,0,0,0}, SP[4] = {0,0,0,0};
  int cur_d = -1;

  // ---- prologue: pair + P1 fragments for the first 48-edge tile ----
  int2 spA, spB, spC;
  bf16x8 a1A, a1B, a1C;
  {
    int ecA = lo + t;      if(ecA >= hi) ecA = hi-1;
    int ecB = lo + 16 + t; if(ecB >= hi) ecB = hi-1;
    int ecC = lo + 32 + t; if(ecC >= hi) ecC = hi-1;
    spA = pair[ecA]; spB = pair[ecB]; spC = pair[ecC];
#pragma unroll
    for(int j=0;j<8;j++){ a1A[j]=0; a1B[j]=0; a1C[j]=0; }
    if(q==0){
      a1A[0] = (short)f2bf(pos[(size_t)spA.y*3+0] - pos[(size_t)spA.x*3+0]);
      a1A[1] = (short)f2bf(pos[(size_t)spA.y*3+1] - pos[(size_t)spA.x*3+1]);
      a1A[2] = (short)f2bf(pos[(size_t)spA.y*3+2] - pos[(size_t)spA.x*3+2]);
      a1B[0] = (short)f2bf(pos[(size_t)spB.y*3+0] - pos[(size_t)spB.x*3+0]);
      a1B[1] = (short)f2bf(pos[(size_t)spB.y*3+1] - pos[(size_t)spB.x*3+1]);
      a1B[2] = (short)f2bf(pos[(size_t)spB.y*3+2] - pos[(size_t)spB.x*3+2]);
      a1C[0] = (short)f2bf(pos[(size_t)spC.y*3+0] - pos[(size_t)spC.x*3+0]);
      a1C[1] = (short)f2bf(pos[(size_t)spC.y*3+1] - pos[(size_t)spC.x*3+1]);
      a1C[2] = (short)f2bf(pos[(size_t)spC.y*3+2] - pos[(size_t)spC.x*3+2]);
    }
  }

  for(int tb = lo; tb < hi; tb += 48){
    bool hasB = (tb+16) < hi, hasC = (tb+32) < hi;
    int didA = spA.y, didB = spB.y, didC = spC.y;

    // ---- TOP: next-tile pair prefetch FIRST ----
    int2 nspA, nspB, nspC;
    {
      int eA = tb + 48 + t; if(eA >= hi) eA = hi-1;
      int eB = tb + 64 + t; if(eB >= hi) eB = hi-1;
      int eC = tb + 80 + t; if(eC >= hi) eC = hi-1;
      nspA = pair[eA]; nspB = pair[eB]; nspC = pair[eC];
    }
    // ---- corr gathers A,B (C staggered after A1-A to cap reg peak) ----
    uint2 adwA[4], aswA[4];
#pragma unroll
    for(int r=0;r<4;r++){
      int e = tb + q*4 + r; if(e >= hi) e = hi-1;
      int2 p = pair[e];
      adwA[r] = ad2[(size_t)p.y*16 + t];
      aswA[r] = as2[(size_t)p.x*16 + t];
    }
    uint2 adwB[4], aswB[4];
#pragma unroll
    for(int r=0;r<4;r++){
      int e = tb + 16 + q*4 + r; if(e >= hi) e = hi-1;
      int2 p = pair[e];
      adwB[r] = ad2[(size_t)p.y*16 + t];
      aswB[r] = as2[(size_t)p.x*16 + t];
    }

    // ---- P1 (3 chains) with prefetched fragments ----
    f32x4 accA[4], accB[4], accC[4];
#pragma unroll
    for(int nt=0;nt<4;nt++){
      bf16x8 wp = fb_load(FB, FB_P1+nt, lane);
      accA[nt] = __builtin_amdgcn_mfma_f32_16x16x32_bf16(a1A, wp, zero, 0,0,0);
      accB[nt] = __builtin_amdgcn_mfma_f32_16x16x32_bf16(a1B, wp, zero, 0,0,0);
      accC[nt] = __builtin_amdgcn_mfma_f32_16x16x32_bf16(a1C, wp, zero, 0,0,0);
    }

    // r1 -> buf0 (rows: A 0-15, B 16-31, C 32-47)
#pragma unroll
    for(int nt=0;nt<4;nt++)
#pragma unroll
      for(int r=0;r<4;r++){
        lb[(     q*4+r)*LROW + nt*16 + t] = f2bf(fmaxf(accA[nt][r] + bp1f[nt], 0.f));
        lb[(16 + q*4+r)*LROW + nt*16 + t] = f2bf(fmaxf(accB[nt][r] + bp1f[nt], 0.f));
        lb[(32 + q*4+r)*LROW + nt*16 + t] = f2bf(fmaxf(accC[nt][r] + bp1f[nt], 0.f));
      }
    ldsorder();                     // F1: compiler order only (no HW drain)

    bf16x8 atA0 = lds_read_chunk(lb32, (t   )*LROWD + q*4);
    bf16x8 atA1 = lds_read_chunk(lb32, (t   )*LROWD + 16 + q*4);
    bf16x8 atB0 = lds_read_chunk(lb32, (t+16)*LROWD + q*4);
    bf16x8 atB1 = lds_read_chunk(lb32, (t+16)*LROWD + 16 + q*4);
    bf16x8 atC0 = lds_read_chunk(lb32, (t+32)*LROWD + q*4);
    bf16x8 atC1 = lds_read_chunk(lb32, (t+32)*LROWD + 16 + q*4);

    // ---- next-tile P1 fragments (used next iter) ----
    bf16x8 na1A, na1B, na1C;
#pragma unroll
    for(int j=0;j<8;j++){ na1A[j]=0; na1B[j]=0; na1C[j]=0; }
    if(q==0){
      na1A[0] = (short)f2bf(pos[(size_t)nspA.y*3+0] - pos[(size_t)nspA.x*3+0]);
      na1A[1] = (short)f2bf(pos[(size_t)nspA.y*3+1] - pos[(size_t)nspA.x*3+1]);
      na1A[2] = (short)f2bf(pos[(size_t)nspA.y*3+2] - pos[(size_t)nspA.x*3+2]);
      na1B[0] = (short)f2bf(pos[(size_t)nspB.y*3+0] - pos[(size_t)nspB.x*3+0]);
      na1B[1] = (short)f2bf(pos[(size_t)nspB.y*3+1] - pos[(size_t)nspB.x*3+1]);
      na1B[2] = (short)f2bf(pos[(size_t)nspB.y*3+2] - pos[(size_t)nspB.x*3+2]);
      na1C[0] = (short)f2bf(pos[(size_t)nspC.y*3+0] - pos[(size_t)nspC.x*3+0]);
      na1C[1] = (short)f2bf(pos[(size_t)nspC.y*3+1] - pos[(size_t)nspC.x*3+1]);
      na1C[2] = (short)f2bf(pos[(size_t)nspC.y*3+2] - pos[(size_t)nspC.x*3+2]);
    }

    // --- P2 -> delta in bf16-packed regs (bp2 folded) ---
    u32 dpA[4][2], dpB[4][2], dpC[4][2];
#pragma unroll
    for(int nt=0;nt<4;nt++){
      bf16x8 w0 = fb_load(FB, FB_P2+nt*2+0, lane);
      bf16x8 w1 = fb_load(FB, FB_P2+nt*2+1, lane);
      f32x4 a = __builtin_amdgcn_mfma_f32_16x16x32_bf16(atA0, w0, zero, 0,0,0);
      a = __builtin_amdgcn_mfma_f32_16x16x32_bf16(atA1, w1, a, 0,0,0);
      f32x4 b = __builtin_amdgcn_mfma_f32_16x16x32_bf16(atB0, w0, zero, 0,0,0);
      b = __builtin_amdgcn_mfma_f32_16x16x32_bf16(atB1, w1, b, 0,0,0);
      f32x4 c = __builtin_amdgcn_mfma_f32_16x16x32_bf16(atC0, w0, zero, 0,0,0);
      c = __builtin_amdgcn_mfma_f32_16x16x32_bf16(atC1, w1, c, 0,0,0);
      dpA[nt][0] = pk2(a[0]+bp2f[nt], a[1]+bp2f[nt]);
      dpA[nt][1] = pk2(a[2]+bp2f[nt], a[3]+bp2f[nt]);
      dpB[nt][0] = pk2(b[0]+bp2f[nt], b[1]+bp2f[nt]);
      dpB[nt][1] = pk2(b[2]+bp2f[nt], b[3]+bp2f[nt]);
      dpC[nt][0] = pk2(c[0]+bp2f[nt], c[1]+bp2f[nt]);
      dpC[nt][1] = pk2(c[2]+bp2f[nt], c[3]+bp2f[nt]);
    }

    // --- A1 chain A -> buf1 rows 0-15 (last use of atA*, adwA/aswA) ---
#pragma unroll
    for(int nt=0;nt<4;nt++){
      f32x4 a = __builtin_amdgcn_mfma_f32_16x16x32_bf16(atA0, fb_load(FB, FB_A1+nt*2+0, lane), zero, 0,0,0);
      a = __builtin_amdgcn_mfma_f32_16x16x32_bf16(atA1, fb_load(FB, FB_A1+nt*2+1, lane), a, 0,0,0);
#pragma unroll
      for(int r=0;r<4;r++){
        u32 dw = (nt&2)? adwA[r].y : adwA[r].x;
        u32 sw = (nt&2)? aswA[r].y : aswA[r].x;
        float c = ((nt&1)? bfh(dw) : bfl(dw)) - ((nt&1)? bfh(sw) : bfl(sw));
        lu[(q*4+r)*LROW + nt*16 + t] = f2bf(fmaxf(a[r] + c + baf[nt], 0.f));
      }
    }

    // --- corr gather C (regs freed by A1-A; hides under A1-B/C MFMAs) ---
    uint2 adwC[4], aswC[4];
#pragma unroll
    for(int r=0;r<4;r++){
      int e = tb + 32 + q*4 + r; if(e >= hi) e = hi-1;
      int2 p = pair[e];
      adwC[r] = ad2[(size_t)p.y*16 + t];
      aswC[r] = as2[(size_t)p.x*16 + t];
    }

    // --- A1 chain B -> buf1 rows 16-31 ---
#pragma unroll
    for(int nt=0;nt<4;nt++){
      f32x4 b = __builtin_amdgcn_mfma_f32_16x16x32_bf16(atB0, fb_load(FB, FB_A1+nt*2+0, lane), zero, 0,0,0);
      b = __builtin_amdgcn_mfma_f32_16x16x32_bf16(atB1, fb_load(FB, FB_A1+nt*2+1, lane), b, 0,0,0);
#pragma unroll
      for(int r=0;r<4;r++){
        u32 dw = (nt&2)? adwB[r].y : adwB[r].x;
        u32 sw = (nt&2)? aswB[r].y : aswB[r].x;
        float c = ((nt&1)? bfh(dw) : bfl(dw)) - ((nt&1)? bfh(sw) : bfl(sw));
        lu[(16 + q*4+r)*LROW + nt*16 + t] = f2bf(fmaxf(b[r] + c + baf[nt], 0.f));
      }
    }
    // --- A1 chain C -> buf1 rows 32-47 ---
#pragma unroll
    for(int nt=0;nt<4;nt++){
      f32x4 c4 = __builtin_amdgcn_mfma_f32_16x16x32_bf16(atC0, fb_load(FB, FB_A1+nt*2+0, lane), zero, 0,0,0);
      c4 = __builtin_amdgcn_mfma_f32_16x16x32_bf16(atC1, fb_load(FB, FB_A1+nt*2+1, lane), c4, 0,0,0);
#pragma unroll
      for(int r=0;r<4;r++){
        u32 dw = (nt&2)? adwC[r].y : adwC[r].x;
        u32 sw = (nt&2)? aswC[r].y : aswC[r].x;
        float c = ((nt&1)? bfh(dw) : bfl(dw)) - ((nt&1)? bfh(sw) : bfl(sw));
        lu[(32 + q*4+r)*LROW + nt*16 + t] = f2bf(fmaxf(c4[r] + c + baf[nt], 0.f));
      }
    }

    // v-gathers (use after A2 per chain)
    uint2 vrawA[4], vrawB[4], vrawC[4];
#pragma unroll
    for(int r=0;r<4;r++){
      int e = tb + q*4 + r; if(e >= hi) e = hi-1;
      vrawA[r] = v2[(size_t)pair[e].x*16 + t];
    }
#pragma unroll
    for(int r=0;r<4;r++){
      int e = tb + 16 + q*4 + r; if(e >= hi) e = hi-1;
      vrawB[r] = v2[(size_t)pair[e].x*16 + t];
    }
#pragma unroll
    for(int r=0;r<4;r++){
      int e = tb + 32 + q*4 + r; if(e >= hi) e = hi-1;
      vrawC[r] = v2[(size_t)pair[e].x*16 + t];
    }
    ldsorder();                     // F2: compiler order only (no HW drain)

    bf16x8 auA0 = lds_read_chunk(lu32, (t   )*LROWD + q*4);
    bf16x8 auA1 = lds_read_chunk(lu32, (t   )*LROWD + 16 + q*4);
    bf16x8 auB0 = lds_read_chunk(lu32, (t+16)*LROWD + q*4);
    bf16x8 auB1 = lds_read_chunk(lu32, (t+16)*LROWD + 16 + q*4);
    bf16x8 auC0 = lds_read_chunk(lu32, (t+32)*LROWD + q*4);
    bf16x8 auC1 = lds_read_chunk(lu32, (t+32)*LROWD + 16 + q*4);

    // --- A2 -> w=exp -> aggregate; chains sequentially (wv/pd reused) ---
    float wv[4][4], pd[4][4];
#pragma unroll
    for(int nt=0;nt<4;nt++){
      bf16x8 w0 = fb_load(FB, FB_A2+nt*2+0, lane);
      bf16x8 w1 = fb_load(FB, FB_A2+nt*2+1, lane);
      f32x4 a = __builtin_amdgcn_mfma_f32_16x16x32_bf16(auA0, w0, zero, 0,0,0);
      a = __builtin_amdgcn_mfma_f32_16x16x32_bf16(auA1, w1, a, 0,0,0);
#pragma unroll
      for(int r=0;r<4;r++)
        wv[nt][r] = ((tb + q*4 + r) < hi) ? __expf(fminf(a[r] + ba2f[nt], 80.f)) : 0.f;
    }
#pragma unroll
    for(int r=0;r<4;r++){
      float va[4] = { bfl(vrawA[r].x), bfh(vrawA[r].x), bfl(vrawA[r].y), bfh(vrawA[r].y) };
#pragma unroll
      for(int nt=0;nt<4;nt++){
        u32 dw = dpA[nt][r>>1];
        pd[r][nt] = va[nt] + ((r&1)? bfh(dw) : bfl(dw));
      }
    }
    agg_tile(tb, hi, lo, didA, wv, pd, cur_d, numP, SP, row_start, num, S, q, t);

    if(hasB){
#pragma unroll
      for(int nt=0;nt<4;nt++){
        bf16x8 w0 = fb_load(FB, FB_A2+nt*2+0, lane);
        bf16x8 w1 = fb_load(FB, FB_A2+nt*2+1, lane);
        f32x4 b = __builtin_amdgcn_mfma_f32_16x16x32_bf16(auB0, w0, zero, 0,0,0);
        b = __builtin_amdgcn_mfma_f32_16x16x32_bf16(auB1, w1, b, 0,0,0);
#pragma unroll
        for(int r=0;r<4;r++)
          wv[nt][r] = ((tb + 16 + q*4 + r) < hi) ? __expf(fminf(b[r] + ba2f[nt], 80.f)) : 0.f;
      }
#pragma unroll
      for(int r=0;r<4;r++){
        float vb[4] = { bfl(vrawB[r].x), bfh(vrawB[r].x), bfl(vrawB[r].y), bfh(vrawB[r].y) };
#pragma unroll
        for(int nt=0;nt<4;nt++){
          u32 dw = dpB[nt][r>>1];
          pd[r][nt] = vb[nt] + ((r&1)? bfh(dw) : bfl(dw));
        }
      }
      agg_tile(tb+16, hi, lo, didB, wv, pd, cur_d, numP, SP, row_start, num, S, q, t);
    }

    if(hasC){
#pragma unroll
      for(int nt=0;nt<4;nt++){
        bf16x8 w0 = fb_load(FB, FB_A2+nt*2+0, lane);
        bf16x8 w1 = fb_load(FB, FB_A2+nt*2+1, lane);
        f32x4 c4 = __builtin_amdgcn_mfma_f32_16x16x32_bf16(auC0, w0, zero, 0,0,0);
        c4 = __builtin_amdgcn_mfma_f32_16x16x32_bf16(auC1, w1, c4, 0,0,0);
#pragma unroll
        for(int r=0;r<4;r++)
          wv[nt][r] = ((tb + 32 + q*4 + r) < hi) ? __expf(fminf(c4[r] + ba2f[nt], 80.f)) : 0.f;
      }
#pragma unroll
      for(int r=0;r<4;r++){
        float vc[4] = { bfl(vrawC[r].x), bfh(vrawC[r].x), bfl(vrawC[r].y), bfh(vrawC[r].y) };
#pragma unroll
        for(int nt=0;nt<4;nt++){
          u32 dw = dpC[nt][r>>1];
          pd[r][nt] = vc[nt] + ((r&1)? bfh(dw) : bfl(dw));
        }
      }
      agg_tile(tb+32, hi, lo, didC, wv, pd, cur_d, numP, SP, row_start, num, S, q, t);
    }

    // ---- rotate pipeline state ----
    spA = nspA; spB = nspB; spC = nspC;
    a1A = na1A; a1B = na1B; a1C = na1C;
  }
  flushseg(cur_d, numP, SP, row_start, num, S, lo, hi, q, t);
}

// ---------- out = relu((num/S) @ Wout + bout), MFMA ----------
__global__ __launch_bounds__(256) void k_out_m(
  const float* __restrict__ num, const float* __restrict__ S,
  const float* __restrict__ Bf, const u16* __restrict__ FB,
  float* __restrict__ out, int N, int ntiles)
{
  int lane = threadIdx.x & 63, warp = threadIdx.x >> 6;
  int t = lane & 15, q = lane >> 4;
  int tile = blockIdx.x*4 + warp;
  if(tile >= ntiles) return;
  int r0 = tile*16;
  int row = r0 + t; if(row >= N) row = N-1;
  const float4* n4 = (const float4*)(num + (size_t)row*64);
  const float4* s4 = (const float4*)(S   + (size_t)row*64);
  bf16x8 af[2];
#pragma unroll
  for(int s=0;s<2;s++){
    float4 n0 = n4[s*8 + q*2], n1 = n4[s*8 + q*2 + 1];
    float4 s0 = s4[s*8 + q*2], s1 = s4[s*8 + q*2 + 1];
    af[s][0]=(short)f2bf(n0.x/(s0.x+1e-16f)); af[s][1]=(short)f2bf(n0.y/(s0.y+1e-16f));
    af[s][2]=(short)f2bf(n0.z/(s0.z+1e-16f)); af[s][3]=(short)f2bf(n0.w/(s0.w+1e-16f));
    af[s][4]=(short)f2bf(n1.x/(s1.x+1e-16f)); af[s][5]=(short)f2bf(n1.y/(s1.y+1e-16f));
    af[s][6]=(short)f2bf(n1.z/(s1.z+1e-16f)); af[s][7]=(short)f2bf(n1.w/(s1.w+1e-16f));
  }
  f32x4 zero = {0.f,0.f,0.f,0.f};
#pragma unroll
  for(int nt=0;nt<4;nt++){
    f32x4 a = __builtin_amdgcn_mfma_f32_16x16x32_bf16(af[0], fb_load(FB, FB_OUT+nt*2+0, lane), zero, 0,0,0);
    a = __builtin_amdgcn_mfma_f32_16x16x32_bf16(af[1], fb_load(FB, FB_OUT+nt*2+1, lane), a, 0,0,0);
    float b = Bf[320 + nt*16 + t];
#pragma unroll
    for(int r=0;r<4;r++){
      int rr = r0 + q*4 + r;
      if(rr < N) out[(size_t)rr*64 + nt*16 + t] = fmaxf(a[r] + b, 0.f);
    }
  }
}

extern "C" void kernel_launch(void* const* d_in, const int* in_sizes, int n_in,
                              void* d_out, int out_size, void* d_ws, size_t ws_size,
                              hipStream_t stream){
  const float* x   =(const float*)d_in[0];
  const float* pos =(const float*)d_in[1];
  const int*   ei  =(const int*)d_in[2];
  const float* Win =(const float*)d_in[3];  const float* bin=(const float*)d_in[4];
  const float* Wlin=(const float*)d_in[5];  const float* Wsrc=(const float*)d_in[6];
  const float* Wdst=(const float*)d_in[7];
  const float* Wp1 =(const float*)d_in[8];  const float* bp1=(const float*)d_in[9];
  const float* Wp2 =(const float*)d_in[10]; const float* bp2=(const float*)d_in[11];
  const float* Wa1 =(const float*)d_in[12]; const float* ba1=(const float*)d_in[13];
  const float* Wa2 =(const float*)d_in[14]; const float* ba2=(const float*)d_in[15];
  const float* Wout=(const float*)d_in[16]; const float* bout=(const float*)d_in[17];
  int N = in_sizes[0]/64;
  int E = in_sizes[2]/2;

  float* Bf    = (float*)d_ws;                     // 384 f32
  u16*   FB    = (u16*)(Bf + NBIAS);               // NFRAG*64*8 u16 (69632 B)
  u16*   vfb   = FB + (size_t)NFRAG*64*8;          // [N*64] bf16, permuted
  u16*   asb   = vfb + (size_t)N*64;               // [N*64] bf16, permuted (h@Wsa)
  u16*   adb   = asb + (size_t)N*64;               // [N*64] bf16, permuted (h@Wda)
  float* S     = (float*)(adb + (size_t)N*64);
  float* num   = S    + (size_t)N*64;
  int* deg       = (int*)(num + (size_t)N*64);
  int* cursor    = deg + N;
  int* row_start = cursor + N;
  int* bsum      = row_start + (N+1);
  int* bsoff     = bsum + 256;
  int2* pair     = (int2*)(bsoff + 256);

  int ntiles = (N+15)/16;
  int nsuper = (E+47)/48;          // 48-edge supertiles (triple-chain)
  // single scheduling round at 2 blocks/CU: 2048 waves -> 463 blocks <= 512 slots.
  int total_waves = 2048;
  int spw = (nsuper + total_waves - 1) / total_waves;
  int nwaves = (nsuper + spw - 1) / spw;
  int eblocks = (nwaves + 3) / 4;
  int nscb = (N+255)/256;
  int hblocks = (E+255)/256;
  int nodeblocks = (ntiles+3)/4;
  int sblocks = (E+255)/256;
  int zblocks = 512;
  int zcount4 = N*32;              // 2*N*64 floats as float4

  hipMemsetAsync(deg, 0, (size_t)2*N*sizeof(int), stream);
  k_prep<<<dim3(PREP_BLOCKS + hblocks), dim3(256), 0, stream>>>(
      Win,Wlin,Wsrc,Wdst,Wp1,Wp2,Wa1,Wa2,Wout,
      bin,bp1,bp2,ba1,ba2,bout, Bf, FB, ei, deg, E);
  k_scanA<<<dim3(nscb), dim3(256), 0, stream>>>(deg, row_start, bsum, N);
  k_scanBC<<<dim3(nscb), dim3(256), 0, stream>>>(bsum, row_start, nscb, N);
  // scatter ∥ node ∥ zero(S,num)
  k_mid2<<<dim3(sblocks + nodeblocks + zblocks), dim3(256), 0, stream>>>(
      ei, row_start, cursor, pair, E, sblocks,
      x, Bf, FB, vfb, asb, adb, N, ntiles, nodeblocks,
      S, zcount4, zblocks);
  k_edge_p10<<<dim3(eblocks), dim3(256), 0, stream>>>(row_start, pair, pos, Bf, FB,
                                                      vfb, asb, adb, S, num, E, nsuper, spw);
  k_out_m<<<dim3((ntiles+3)/4), dim3(256), 0, stream>>>(num, S, Bf, FB, (float*)d_out, N, ntiles);
}

// Round 12
// 323.800 us; speedup vs baseline: 1.2956x; 1.2956x over previous
//
#include <hip/hip_runtime.h>

typedef unsigned short u16;
typedef unsigned int   u32;
typedef unsigned long long u64;
typedef __attribute__((ext_vector_type(8))) short bf16x8;
typedef __attribute__((ext_vector_type(4))) float f32x4;

#define DEV static __device__ __forceinline__

DEV u16 f2bf(float f){ union{float f; u32 i;} v; v.f=f; u32 u=v.i;
                       return (u16)((u + 0x7FFFu + ((u>>16)&1u))>>16); }
DEV float bf2f(u16 u){ union{u32 i; float f;} v; v.i=((u32)u)<<16; return v.f; }
DEV float bfl(u32 w){ return bf2f((u16)(w & 0xffffu)); }
DEV float bfh(u32 w){ return bf2f((u16)(w >> 16)); }
DEV u32 pk2(float a, float b){ return (u32)f2bf(a) | ((u32)f2bf(b) << 16); }
// LOAD-BEARING (R12 post-mortem): LDS stores are u16, reads are u32 — without the
// "memory" clobber the compiler's alias analysis reorders them (absmax=inf).
DEV void ldsfence(){ asm volatile("s_waitcnt lgkmcnt(0)" ::: "memory"); }
// R9 (verified): compiler-ordering barrier WITHOUT the hardware drain. Per-warp-private
// LDS + CDNA per-wave in-order DS pipe => intra-wave RAW/WAR satisfied by program
// order; compiler inserts counted lgkmcnt at first consumer. absmax held in R9.
DEV void ldsorder(){ asm volatile("" ::: "memory"); }

// ---- bias slab (f32): bin,bp1,bp2,b_att1(fused),ba2,bout ----
#define NBIAS 384
// ---- fragment buffer FB: [frag][lane][8] u16 ----
#define FB_P1 0
#define FB_P2 4
#define FB_A1 12   // fused Wp2@Wa1
#define FB_A2 20
#define FB_IN 28
#define FB_LIN 36
#define FB_SRC 44  // fused Wsrc@Wa1
#define FB_DST 52  // fused Wdst@Wa1
#define FB_OUT 60
#define NFRAG 68

// LDS row stride: 70 u16 = 35 dwords -> fragment reads ~2-way bank alias (free, m136).
#define LROW 70
#define LROWD 35

DEV bf16x8 fb_load(const u16* __restrict__ FB, int frag, int lane){
  union{ uint4 u; bf16x8 v; } w;
  w.u = *(const uint4*)(FB + ((size_t)(frag*64+lane))*8);
  return w.v;
}
DEV bf16x8 lds_read_chunk(const u32* l32, int dw){
  union{ u32 d[4]; bf16x8 v; } u;
#pragma unroll
  for(int p=0;p<4;p++) u.d[p] = l32[dw+p];
  return u.v;
}

// ---------- prep: bias slab + fragment buffer + degree histogram (merged) ----------
#define PREP_BLOCKS 19
__global__ __launch_bounds__(256) void k_prep(
  const float* __restrict__ Win, const float* __restrict__ Wlin,
  const float* __restrict__ Wsrc, const float* __restrict__ Wdst,
  const float* __restrict__ Wp1, const float* __restrict__ Wp2,
  const float* __restrict__ Wa1, const float* __restrict__ Wa2,
  const float* __restrict__ Wout,
  const float* __restrict__ bin, const float* __restrict__ bp1, const float* __restrict__ bp2,
  const float* __restrict__ ba1, const float* __restrict__ ba2, const float* __restrict__ bout,
  float* __restrict__ Bf, u16* __restrict__ FB,
  const int* __restrict__ ei, int* __restrict__ deg, int E)
{
  if(blockIdx.x >= PREP_BLOCKS){
    int e = (blockIdx.x - PREP_BLOCKS)*256 + threadIdx.x;
    if(e < E) atomicAdd(&deg[ei[(size_t)E + e]], 1);
    return;
  }
  int idx = blockIdx.x*256 + threadIdx.x;
  if(idx < NBIAS){
    int which = idx >> 6, c = idx & 63;
    if(which == 3){                         // fused attn-L1 bias: bp2@Wa1 + ba1
      float sacc = ba1[c];
      for(int k=0;k<64;k++) sacc += bp2[k]*Wa1[k*64+c];
      Bf[idx] = sacc;
    } else {
      const float* b;
      switch(which){ case 0:b=bin;break; case 1:b=bp1;break; case 2:b=bp2;break;
                     case 4:b=ba2;break; default:b=bout;break; }
      Bf[idx] = b[c];
    }
  } else if(idx < NBIAS + NFRAG*64){
    int j = idx - NBIAS;
    int frag = j >> 6, lane = j & 63;
    int t = lane & 15, q = lane >> 4;
    const float* src = nullptr; const float* fuse = nullptr;
    int K = 64, nt, s;
    if(frag < 4){ src = Wp1; K = 3; nt = frag; s = 0; }
    else if(frag < 12){ int g=frag-4;  src=Wp2;  nt=g>>1; s=g&1; }
    else if(frag < 20){ int g=frag-12; fuse=Wp2; nt=g>>1; s=g&1; }   // Wp2@Wa1
    else if(frag < 28){ int g=frag-20; src=Wa2;  nt=g>>1; s=g&1; }
    else if(frag < 36){ int g=frag-28; src=Win;  nt=g>>1; s=g&1; }
    else if(frag < 44){ int g=frag-36; src=Wlin; nt=g>>1; s=g&1; }
    else if(frag < 52){ int g=frag-44; fuse=Wsrc; nt=g>>1; s=g&1; }  // Wsrc@Wa1
    else if(frag < 60){ int g=frag-52; fuse=Wdst; nt=g>>1; s=g&1; }  // Wdst@Wa1
    else              { int g=frag-60; src=Wout; nt=g>>1; s=g&1; }
    u16* dst = FB + ((size_t)(frag*64+lane))*8;
    if(fuse){
      int col = nt*16 + t;
#pragma unroll
      for(int jj=0;jj<8;jj++){
        int k = s*32 + q*8 + jj;
        const float* ar = fuse + k*64;
        float accv = 0.f;
        for(int m=0;m<64;m++) accv += ar[m] * Wa1[m*64+col];
        dst[jj] = f2bf(accv);
      }
    } else {
#pragma unroll
      for(int jj=0;jj<8;jj++){
        int k = s*32 + q*8 + jj;
        dst[jj] = (k<K) ? f2bf(src[k*64 + nt*16 + t]) : (u16)0;
      }
    }
  }
}

// ---------- CSR scans ----------
__global__ __launch_bounds__(256) void k_scanA(const int* __restrict__ deg,
    int* __restrict__ row_start, int* __restrict__ bsum, int N){
  __shared__ int b[256];
  int tid = threadIdx.x, i = blockIdx.x*256 + tid;
  int v = (i<N) ? deg[i] : 0;
  b[tid] = v; __syncthreads();
#pragma unroll
  for(int off=1; off<256; off<<=1){
    int u = (tid>=off) ? b[tid-off] : 0;
    __syncthreads(); b[tid] += u; __syncthreads();
  }
  if(i<N) row_start[i] = b[tid] - v;
  if(tid==255) bsum[blockIdx.x] = b[255];
}

__global__ __launch_bounds__(256) void k_scanBC(
  const int* __restrict__ bsum, int* __restrict__ row_start, int nb, int N)
{
  __shared__ int b[256];
  __shared__ int ex[256];
  int tid = threadIdx.x;
  int v = (tid<nb) ? bsum[tid] : 0;
  b[tid] = v; __syncthreads();
#pragma unroll
  for(int off=1; off<256; off<<=1){
    int u = (tid>=off) ? b[tid-off] : 0;
    __syncthreads(); b[tid] += u; __syncthreads();
  }
  ex[tid] = b[tid] - v;        // exclusive prefix
  __syncthreads();
  int off0 = ex[blockIdx.x];
  int i = blockIdx.x*256 + tid;
  if(i<N) row_start[i] += off0;
  if(blockIdx.x==0 && tid==255) row_start[N] = b[255];
}

// ---------- merged mid-stage v2: scatter ∥ node-side MFMA ∥ S/num zero-fill ----------
__global__ __launch_bounds__(256) void k_mid2(
  const int* __restrict__ ei, const int* __restrict__ row_start, int* __restrict__ cursor,
  int2* __restrict__ pair, int E, int sblocks,
  const float* __restrict__ x, const float* __restrict__ Bf, const u16* __restrict__ FB,
  u16* __restrict__ vf, u16* __restrict__ asof, u16* __restrict__ adof,
  int N, int ntiles, int nodeblocks,
  float* __restrict__ Z, int zcount4, int zblocks)
{
  __shared__ u16 sc16[4][16*LROW];
  int bid = blockIdx.x;

  if(bid < sblocks){
    int e = bid*256 + threadIdx.x;
    if(e < E){
      int d = ei[(size_t)E + e];
      int p = atomicAdd(&cursor[d], 1);
      int2 pr; pr.x = ei[e]; pr.y = d;
      pair[row_start[d] + p] = pr;
    }
    return;
  }
  if(bid >= sblocks + nodeblocks){
    int zb = bid - sblocks - nodeblocks;
    float4* Z4 = (float4*)Z;
    float4 z = {0.f,0.f,0.f,0.f};
    for(int i = zb*256 + threadIdx.x; i < zcount4; i += zblocks*256) Z4[i] = z;
    return;
  }

  int lane = threadIdx.x & 63, warp = threadIdx.x >> 6;
  int t = lane & 15, q = lane >> 4;
  int tile = (bid - sblocks)*4 + warp;
  if(tile >= ntiles) return;
  u16* lb = sc16[warp]; u32* lb32 = (u32*)lb;
  int r0 = tile*16;
  int row = r0 + t; if(row >= N) row = N-1;

  const float4* x4 = (const float4*)(x + (size_t)row*64);
  bf16x8 xa[2];
#pragma unroll
  for(int s=0;s<2;s++){
    float4 u0 = x4[s*8 + q*2], u1 = x4[s*8 + q*2 + 1];
    xa[s][0]=(short)f2bf(u0.x); xa[s][1]=(short)f2bf(u0.y);
    xa[s][2]=(short)f2bf(u0.z); xa[s][3]=(short)f2bf(u0.w);
    xa[s][4]=(short)f2bf(u1.x); xa[s][5]=(short)f2bf(u1.y);
    xa[s][6]=(short)f2bf(u1.z); xa[s][7]=(short)f2bf(u1.w);
  }
  f32x4 zero = {0.f,0.f,0.f,0.f};
  f32x4 acc[4];
#pragma unroll
  for(int nt=0;nt<4;nt++){
    acc[nt] = __builtin_amdgcn_mfma_f32_16x16x32_bf16(xa[0], fb_load(FB, FB_IN+nt*2+0, lane), zero, 0,0,0);
    acc[nt] = __builtin_amdgcn_mfma_f32_16x16x32_bf16(xa[1], fb_load(FB, FB_IN+nt*2+1, lane), acc[nt], 0,0,0);
  }
#pragma unroll
  for(int nt=0;nt<4;nt++)
#pragma unroll
    for(int r=0;r<4;r++)
      lb[(q*4+r)*LROW + nt*16 + t] = f2bf(fmaxf(acc[nt][r] + Bf[nt*16+t], 0.f));
  ldsfence();
  bf16x8 h0 = lds_read_chunk(lb32, t*LROWD + q*4);
  bf16x8 h1 = lds_read_chunk(lb32, t*LROWD + 16 + q*4);

  const int fb0[3] = {FB_LIN, FB_SRC, FB_DST};
  u16* Os[3] = {vf, asof, adof};
#pragma unroll
  for(int mtx=0; mtx<3; mtx++){
    f32x4 av[4];
#pragma unroll
    for(int nt=0;nt<4;nt++){
      av[nt] = __builtin_amdgcn_mfma_f32_16x16x32_bf16(h0, fb_load(FB, fb0[mtx]+nt*2+0, lane), zero, 0,0,0);
      av[nt] = __builtin_amdgcn_mfma_f32_16x16x32_bf16(h1, fb_load(FB, fb0[mtx]+nt*2+1, lane), av[nt], 0,0,0);
    }
    u16* O = Os[mtx];
#pragma unroll
    for(int r=0;r<4;r++){
      int rr = r0 + q*4 + r;
      if(rr < N){
        uint2 o;
        o.x = (u32)f2bf(av[0][r]) | ((u32)f2bf(av[1][r]) << 16);
        o.y = (u32)f2bf(av[2][r]) | ((u32)f2bf(av[3][r]) << 16);
        *(uint2*)(O + (size_t)rr*64 + t*4) = o;
      }
    }
  }
}

// ---------- segment flush ----------
DEV void flushseg(int d, float* numP, float* SP, const int* __restrict__ row_start,
                  float* __restrict__ num, float* __restrict__ S,
                  int lo, int hi, int q, int t){
  if(d < 0) return;
#pragma unroll
  for(int nt=0;nt<4;nt++){
    numP[nt] += __shfl_xor(numP[nt], 16, 64);
    numP[nt] += __shfl_xor(numP[nt], 32, 64);
    SP[nt]   += __shfl_xor(SP[nt],   16, 64);
    SP[nt]   += __shfl_xor(SP[nt],   32, 64);
  }
  bool partial = (row_start[d] < lo) || (row_start[d+1] > hi);
  if(q==0){
#pragma unroll
    for(int nt=0;nt<4;nt++){
      size_t off = (size_t)d*64 + nt*16 + t;
      if(partial){ atomicAdd(&num[off], numP[nt]); atomicAdd(&S[off], SP[nt]); }
      else       { num[off] = numP[nt]; S[off] = SP[nt]; }
    }
  }
#pragma unroll
  for(int nt=0;nt<4;nt++){ numP[nt]=0.f; SP[nt]=0.f; }
}

// ---------- segmented accumulate for one 16-edge tile ----------
DEV void agg_tile(int tbase, int hi_w, int lo_w, int did,
                  const float wv[4][4], const float pd[4][4],
                  int& cur_d, float* numP, float* SP,
                  const int* __restrict__ row_start,
                  float* __restrict__ num, float* __restrict__ S, int q, int t){
  int m = 0;
  while(m < 16){
    int d0 = __shfl(did, m, 64);
    u32 same = (u32)(__ballot(did == d0) & 0xFFFFull);
    u32 rest = ~(same >> m);
    int len = __ffs(rest) - 1;
    int m1 = m + len;
    if(d0 != cur_d){
      flushseg(cur_d, numP, SP, row_start, num, S, lo_w, hi_w, q, t);
      cur_d = d0;
    }
#pragma unroll
    for(int r=0;r<4;r++){
      int mm = q*4 + r;
      bool use = (mm >= m) && (mm < m1) && ((tbase+mm) < hi_w);
      if(use){
#pragma unroll
        for(int nt=0;nt<4;nt++){
          numP[nt] += wv[nt][r] * pd[r][nt];
          SP[nt]   += wv[nt][r];
        }
      }
    }
    m = m1;
  }
}

// ---------- packed edge pipeline v11: R9 (verified 131us) + s_setprio on MFMA ----------
// (Resubmit: R11 bench failed on container acquisition, kernel never ran.)
// R10 post-mortem: triple-chain spilled (total reg budget at (256,2) = 256 incl AGPR;
// dual-chain IS the ILP ceiling). Revert to R9 exactly; add T5 setprio hints around
// MFMA clusters. k_edge waves are INDEPENDENT (per-warp LDS, no barriers) — the
// m191 attn regime where setprio measured +4-7% (the GEMM null was lockstep waves).
__global__ __launch_bounds__(256,2) void k_edge_p11(
  const int* __restrict__ row_start, const int2* __restrict__ pair,
  const float* __restrict__ pos, const float* __restrict__ Bf, const u16* __restrict__ FB,
  const u16* __restrict__ vf, const u16* __restrict__ asof, const u16* __restrict__ adof,
  float* __restrict__ S, float* __restrict__ num, int E, int nsuper, int spw)
{
  __shared__ u16 sc16[4][2*32*LROW];   // per-warp: buf0 = r1/at, buf1 = u/au
  int lane = threadIdx.x & 63, warp = threadIdx.x >> 6;
  int t = lane & 15, q = lane >> 4;
  int wid = blockIdx.x*4 + warp;
  int s0 = wid*spw, s1 = s0 + spw;
  if(s0 >= nsuper) return;
  if(s1 > nsuper) s1 = nsuper;
  int lo = s0*32, hi = s1*32; if(hi > E) hi = E;
  u16* lb = sc16[warp];             u32* lb32 = (u32*)lb;
  u16* lu = sc16[warp] + 32*LROW;   u32* lu32 = (u32*)lu;

  float bp1f[4], bp2f[4], baf[4], ba2f[4];
#pragma unroll
  for(int nt=0;nt<4;nt++){
    bp1f[nt]=Bf[ 64+nt*16+t]; bp2f[nt]=Bf[128+nt*16+t];
    baf[nt] =Bf[192+nt*16+t]; ba2f[nt]=Bf[256+nt*16+t];   // baf = bp2@Wa1 + ba1 (fused)
  }
  const uint2* ad2 = (const uint2*)adof;   // permuted: [node][t*4+nt]
  const uint2* as2 = (const uint2*)asof;
  const uint2* v2  = (const uint2*)vf;
  f32x4 zero = {0.f,0.f,0.f,0.f};
  float numP[4] = {0,0,0,0}, SP[4] = {0,0,0,0};
  int cur_d = -1;

  // ---- prologue: pair + P1 fragments for the first tile ----
  int2 spA, spB;
  bf16x8 a1A, a1B;
  {
    int ecA = lo + t;      if(ecA >= hi) ecA = hi-1;
    int ecB = lo + 16 + t; if(ecB >= hi) ecB = hi-1;
    spA = pair[ecA]; spB = pair[ecB];
#pragma unroll
    for(int j=0;j<8;j++){ a1A[j]=0; a1B[j]=0; }
    if(q==0){
      a1A[0] = (short)f2bf(pos[(size_t)spA.y*3+0] - pos[(size_t)spA.x*3+0]);
      a1A[1] = (short)f2bf(pos[(size_t)spA.y*3+1] - pos[(size_t)spA.x*3+1]);
      a1A[2] = (short)f2bf(pos[(size_t)spA.y*3+2] - pos[(size_t)spA.x*3+2]);
      a1B[0] = (short)f2bf(pos[(size_t)spB.y*3+0] - pos[(size_t)spB.x*3+0]);
      a1B[1] = (short)f2bf(pos[(size_t)spB.y*3+1] - pos[(size_t)spB.x*3+1]);
      a1B[2] = (short)f2bf(pos[(size_t)spB.y*3+2] - pos[(size_t)spB.x*3+2]);
    }
  }

  for(int tb = lo; tb < hi; tb += 32){
    bool hasB = (tb+16) < hi;
    int didA = spA.y, didB = spB.y;

    // ---- TOP: next-tile pair prefetch FIRST (first consumed after F1) ----
    int2 nspA, nspB;
    {
      int eA = tb + 32 + t; if(eA >= hi) eA = hi-1;
      int eB = tb + 48 + t; if(eB >= hi) eB = hi-1;
      nspA = pair[eA]; nspB = pair[eB];
    }
    // ---- then all gathers for THIS tile, in use order (pair lines L1-hot) ----
    uint2 adwA[4], aswA[4];
#pragma unroll
    for(int r=0;r<4;r++){
      int e = tb + q*4 + r; if(e >= hi) e = hi-1;
      int2 p = pair[e];
      adwA[r] = ad2[(size_t)p.y*16 + t];
      aswA[r] = as2[(size_t)p.x*16 + t];
    }
    uint2 adwB[4], aswB[4];
#pragma unroll
    for(int r=0;r<4;r++){
      int e = tb + 16 + q*4 + r; if(e >= hi) e = hi-1;
      int2 p = pair[e];
      adwB[r] = ad2[(size_t)p.y*16 + t];
      aswB[r] = as2[(size_t)p.x*16 + t];
    }
    uint2 vrawA[4], vrawB[4];
#pragma unroll
    for(int r=0;r<4;r++){
      int e = tb + q*4 + r; if(e >= hi) e = hi-1;
      vrawA[r] = v2[(size_t)pair[e].x*16 + t];
    }
#pragma unroll
    for(int r=0;r<4;r++){
      int e = tb + 16 + q*4 + r; if(e >= hi) e = hi-1;
      vrawB[r] = v2[(size_t)pair[e].x*16 + t];
    }

    // ---- P1 with prefetched fragments (no pos wait) ----
    f32x4 accA[4], accB[4];
    __builtin_amdgcn_s_setprio(1);
#pragma unroll
    for(int nt=0;nt<4;nt++){
      bf16x8 wp = fb_load(FB, FB_P1+nt, lane);
      accA[nt] = __builtin_amdgcn_mfma_f32_16x16x32_bf16(a1A, wp, zero, 0,0,0);
      accB[nt] = __builtin_amdgcn_mfma_f32_16x16x32_bf16(a1B, wp, zero, 0,0,0);
    }
    __builtin_amdgcn_s_setprio(0);

    // r1 -> buf0. WAR vs prev iter's at-reads: per-wave in-order DS pipe.
#pragma unroll
    for(int nt=0;nt<4;nt++)
#pragma unroll
      for(int r=0;r<4;r++){
        lb[(     q*4+r)*LROW + nt*16 + t] = f2bf(fmaxf(accA[nt][r] + bp1f[nt], 0.f));
        lb[(16 + q*4+r)*LROW + nt*16 + t] = f2bf(fmaxf(accB[nt][r] + bp1f[nt], 0.f));
      }
    ldsorder();                     // F1: compiler order only (no HW drain)

    bf16x8 atA0 = lds_read_chunk(lb32, (t   )*LROWD + q*4);
    bf16x8 atA1 = lds_read_chunk(lb32, (t   )*LROWD + 16 + q*4);
    bf16x8 atB0 = lds_read_chunk(lb32, (t+16)*LROWD + q*4);
    bf16x8 atB1 = lds_read_chunk(lb32, (t+16)*LROWD + 16 + q*4);

    // ---- next-tile P1 fragments (nsp arrived ~1.5K cycles ago; used next iter) ----
    bf16x8 na1A, na1B;
#pragma unroll
    for(int j=0;j<8;j++){ na1A[j]=0; na1B[j]=0; }
    if(q==0){
      na1A[0] = (short)f2bf(pos[(size_t)nspA.y*3+0] - pos[(size_t)nspA.x*3+0]);
      na1A[1] = (short)f2bf(pos[(size_t)nspA.y*3+1] - pos[(size_t)nspA.x*3+1]);
      na1A[2] = (short)f2bf(pos[(size_t)nspA.y*3+2] - pos[(size_t)nspA.x*3+2]);
      na1B[0] = (short)f2bf(pos[(size_t)nspB.y*3+0] - pos[(size_t)nspB.x*3+0]);
      na1B[1] = (short)f2bf(pos[(size_t)nspB.y*3+1] - pos[(size_t)nspB.x*3+1]);
      na1B[2] = (short)f2bf(pos[(size_t)nspB.y*3+2] - pos[(size_t)nspB.x*3+2]);
    }

    // --- P2 -> delta kept in bf16-packed regs (bp2 folded); no LDS for delta ---
    u32 dpA[4][2], dpB[4][2];
    __builtin_amdgcn_s_setprio(1);
#pragma unroll
    for(int nt=0;nt<4;nt++){
      bf16x8 w0 = fb_load(FB, FB_P2+nt*2+0, lane);
      bf16x8 w1 = fb_load(FB, FB_P2+nt*2+1, lane);
      f32x4 a = __builtin_amdgcn_mfma_f32_16x16x32_bf16(atA0, w0, zero, 0,0,0);
      a = __builtin_amdgcn_mfma_f32_16x16x32_bf16(atA1, w1, a, 0,0,0);
      f32x4 b = __builtin_amdgcn_mfma_f32_16x16x32_bf16(atB0, w0, zero, 0,0,0);
      b = __builtin_amdgcn_mfma_f32_16x16x32_bf16(atB1, w1, b, 0,0,0);
      dpA[nt][0] = pk2(a[0]+bp2f[nt], a[1]+bp2f[nt]);
      dpA[nt][1] = pk2(a[2]+bp2f[nt], a[3]+bp2f[nt]);
      dpB[nt][0] = pk2(b[0]+bp2f[nt], b[1]+bp2f[nt]);
      dpB[nt][1] = pk2(b[2]+bp2f[nt], b[3]+bp2f[nt]);
    }
    __builtin_amdgcn_s_setprio(0);

    // --- A1 fused: u = relu(r1@Wp2a1 + (adW - asW) + baf) -> buf1 ---
    // WAR vs prev iter's au-reads: per-wave in-order DS pipe.
    __builtin_amdgcn_s_setprio(1);
#pragma unroll
    for(int nt=0;nt<4;nt++){
      bf16x8 w0 = fb_load(FB, FB_A1+nt*2+0, lane);
      bf16x8 w1 = fb_load(FB, FB_A1+nt*2+1, lane);
      f32x4 a = __builtin_amdgcn_mfma_f32_16x16x32_bf16(atA0, w0, zero, 0,0,0);
      a = __builtin_amdgcn_mfma_f32_16x16x32_bf16(atA1, w1, a, 0,0,0);
#pragma unroll
      for(int r=0;r<4;r++){
        u32 dw = (nt&2)? adwA[r].y : adwA[r].x;
        u32 sw = (nt&2)? aswA[r].y : aswA[r].x;
        float c = ((nt&1)? bfh(dw) : bfl(dw)) - ((nt&1)? bfh(sw) : bfl(sw));
        lu[(q*4+r)*LROW + nt*16 + t] = f2bf(fmaxf(a[r] + c + baf[nt], 0.f));
      }
    }
#pragma unroll
    for(int nt=0;nt<4;nt++){
      bf16x8 w0 = fb_load(FB, FB_A1+nt*2+0, lane);
      bf16x8 w1 = fb_load(FB, FB_A1+nt*2+1, lane);
      f32x4 b = __builtin_amdgcn_mfma_f32_16x16x32_bf16(atB0, w0, zero, 0,0,0);
      b = __builtin_amdgcn_mfma_f32_16x16x32_bf16(atB1, w1, b, 0,0,0);
#pragma unroll
      for(int r=0;r<4;r++){
        u32 dw = (nt&2)? adwB[r].y : adwB[r].x;
        u32 sw = (nt&2)? aswB[r].y : aswB[r].x;
        float c = ((nt&1)? bfh(dw) : bfl(dw)) - ((nt&1)? bfh(sw) : bfl(sw));
        lu[(16 + q*4+r)*LROW + nt*16 + t] = f2bf(fmaxf(b[r] + c + baf[nt], 0.f));
      }
    }
    __builtin_amdgcn_s_setprio(0);
    ldsorder();                     // F2: compiler order only (no HW drain)

    bf16x8 auA0 = lds_read_chunk(lu32, (t   )*LROWD + q*4);
    bf16x8 auA1 = lds_read_chunk(lu32, (t   )*LROWD + 16 + q*4);
    bf16x8 auB0 = lds_read_chunk(lu32, (t+16)*LROWD + q*4);
    bf16x8 auB1 = lds_read_chunk(lu32, (t+16)*LROWD + 16 + q*4);

    // --- A2 -> w=exp, then aggregate; chain A fully, then chain B ---
    float wv[4][4], pd[4][4];
    __builtin_amdgcn_s_setprio(1);
#pragma unroll
    for(int nt=0;nt<4;nt++){
      bf16x8 w0 = fb_load(FB, FB_A2+nt*2+0, lane);
      bf16x8 w1 = fb_load(FB, FB_A2+nt*2+1, lane);
      f32x4 a = __builtin_amdgcn_mfma_f32_16x16x32_bf16(auA0, w0, zero, 0,0,0);
      a = __builtin_amdgcn_mfma_f32_16x16x32_bf16(auA1, w1, a, 0,0,0);
#pragma unroll
      for(int r=0;r<4;r++)
        wv[nt][r] = ((tb + q*4 + r) < hi) ? __expf(fminf(a[r] + ba2f[nt], 80.f)) : 0.f;
    }
    __builtin_amdgcn_s_setprio(0);
#pragma unroll
    for(int r=0;r<4;r++){
      float va[4] = { bfl(vrawA[r].x), bfh(vrawA[r].x), bfl(vrawA[r].y), bfh(vrawA[r].y) };
#pragma unroll
      for(int nt=0;nt<4;nt++){
        u32 dw = dpA[nt][r>>1];
        pd[r][nt] = va[nt] + ((r&1)? bfh(dw) : bfl(dw));
      }
    }
    agg_tile(tb, hi, lo, didA, wv, pd, cur_d, numP, SP, row_start, num, S, q, t);

    if(hasB){
      __builtin_amdgcn_s_setprio(1);
#pragma unroll
      for(int nt=0;nt<4;nt++){
        bf16x8 w0 = fb_load(FB, FB_A2+nt*2+0, lane);
        bf16x8 w1 = fb_load(FB, FB_A2+nt*2+1, lane);
        f32x4 b = __builtin_amdgcn_mfma_f32_16x16x32_bf16(auB0, w0, zero, 0,0,0);
        b = __builtin_amdgcn_mfma_f32_16x16x32_bf16(auB1, w1, b, 0,0,0);
#pragma unroll
        for(int r=0;r<4;r++)
          wv[nt][r] = ((tb + 16 + q*4 + r) < hi) ? __expf(fminf(b[r] + ba2f[nt], 80.f)) : 0.f;
      }
      __builtin_amdgcn_s_setprio(0);
#pragma unroll
      for(int r=0;r<4;r++){
        float vb[4] = { bfl(vrawB[r].x), bfh(vrawB[r].x), bfl(vrawB[r].y), bfh(vrawB[r].y) };
#pragma unroll
        for(int nt=0;nt<4;nt++){
          u32 dw = dpB[nt][r>>1];
          pd[r][nt] = vb[nt] + ((r&1)? bfh(dw) : bfl(dw));
        }
      }
      agg_tile(tb+16, hi, lo, didB, wv, pd, cur_d, numP, SP, row_start, num, S, q, t);
    }

    // ---- rotate pipeline state ----
    spA = nspA; spB = nspB; a1A = na1A; a1B = na1B;
  }
  flushseg(cur_d, numP, SP, row_start, num, S, lo, hi, q, t);
}

// ---------- out = relu((num/S) @ Wout + bout), MFMA ----------
__global__ __launch_bounds__(256) void k_out_m(
  const float* __restrict__ num, const float* __restrict__ S,
  const float* __restrict__ Bf, const u16* __restrict__ FB,
  float* __restrict__ out, int N, int ntiles)
{
  int lane = threadIdx.x & 63, warp = threadIdx.x >> 6;
  int t = lane & 15, q = lane >> 4;
  int tile = blockIdx.x*4 + warp;
  if(tile >= ntiles) return;
  int r0 = tile*16;
  int row = r0 + t; if(row >= N) row = N-1;
  const float4* n4 = (const float4*)(num + (size_t)row*64);
  const float4* s4 = (const float4*)(S   + (size_t)row*64);
  bf16x8 af[2];
#pragma unroll
  for(int s=0;s<2;s++){
    float4 n0 = n4[s*8 + q*2], n1 = n4[s*8 + q*2 + 1];
    float4 s0 = s4[s*8 + q*2], s1 = s4[s*8 + q*2 + 1];
    af[s][0]=(short)f2bf(n0.x/(s0.x+1e-16f)); af[s][1]=(short)f2bf(n0.y/(s0.y+1e-16f));
    af[s][2]=(short)f2bf(n0.z/(s0.z+1e-16f)); af[s][3]=(short)f2bf(n0.w/(s0.w+1e-16f));
    af[s][4]=(short)f2bf(n1.x/(s1.x+1e-16f)); af[s][5]=(short)f2bf(n1.y/(s1.y+1e-16f));
    af[s][6]=(short)f2bf(n1.z/(s1.z+1e-16f)); af[s][7]=(short)f2bf(n1.w/(s1.w+1e-16f));
  }
  f32x4 zero = {0.f,0.f,0.f,0.f};
#pragma unroll
  for(int nt=0;nt<4;nt++){
    f32x4 a = __builtin_amdgcn_mfma_f32_16x16x32_bf16(af[0], fb_load(FB, FB_OUT+nt*2+0, lane), zero, 0,0,0);
    a = __builtin_amdgcn_mfma_f32_16x16x32_bf16(af[1], fb_load(FB, FB_OUT+nt*2+1, lane), a, 0,0,0);
    float b = Bf[320 + nt*16 + t];
#pragma unroll
    for(int r=0;r<4;r++){
      int rr = r0 + q*4 + r;
      if(rr < N) out[(size_t)rr*64 + nt*16 + t] = fmaxf(a[r] + b, 0.f);
    }
  }
}

extern "C" void kernel_launch(void* const* d_in, const int* in_sizes, int n_in,
                              void* d_out, int out_size, void* d_ws, size_t ws_size,
                              hipStream_t stream){
  const float* x   =(const float*)d_in[0];
  const float* pos =(const float*)d_in[1];
  const int*   ei  =(const int*)d_in[2];
  const float* Win =(const float*)d_in[3];  const float* bin=(const float*)d_in[4];
  const float* Wlin=(const float*)d_in[5];  const float* Wsrc=(const float*)d_in[6];
  const float* Wdst=(const float*)d_in[7];
  const float* Wp1 =(const float*)d_in[8];  const float* bp1=(const float*)d_in[9];
  const float* Wp2 =(const float*)d_in[10]; const float* bp2=(const float*)d_in[11];
  const float* Wa1 =(const float*)d_in[12]; const float* ba1=(const float*)d_in[13];
  const float* Wa2 =(const float*)d_in[14]; const float* ba2=(const float*)d_in[15];
  const float* Wout=(const float*)d_in[16]; const float* bout=(const float*)d_in[17];
  int N = in_sizes[0]/64;
  int E = in_sizes[2]/2;

  float* Bf    = (float*)d_ws;                     // 384 f32
  u16*   FB    = (u16*)(Bf + NBIAS);               // NFRAG*64*8 u16 (69632 B)
  u16*   vfb   = FB + (size_t)NFRAG*64*8;          // [N*64] bf16, permuted
  u16*   asb   = vfb + (size_t)N*64;               // [N*64] bf16, permuted (h@Wsa)
  u16*   adb   = asb + (size_t)N*64;               // [N*64] bf16, permuted (h@Wda)
  float* S     = (float*)(adb + (size_t)N*64);
  float* num   = S    + (size_t)N*64;
  int* deg       = (int*)(num + (size_t)N*64);
  int* cursor    = deg + N;
  int* row_start = cursor + N;
  int* bsum      = row_start + (N+1);
  int* bsoff     = bsum + 256;
  int2* pair     = (int2*)(bsoff + 256);

  int ntiles = (N+15)/16;
  int nsuper = (E+31)/32;
  // single scheduling round at 2 blocks/CU: 2048 waves = 512 blocks <= 512 slots.
  int total_waves = 2048;
  int spw = (nsuper + total_waves - 1) / total_waves;
  int nwaves = (nsuper + spw - 1) / spw;
  int eblocks = (nwaves + 3) / 4;
  int nscb = (N+255)/256;
  int hblocks = (E+255)/256;
  int nodeblocks = (ntiles+3)/4;
  int sblocks = (E+255)/256;
  int zblocks = 512;
  int zcount4 = N*32;              // 2*N*64 floats as float4

  hipMemsetAsync(deg, 0, (size_t)2*N*sizeof(int), stream);
  k_prep<<<dim3(PREP_BLOCKS + hblocks), dim3(256), 0, stream>>>(
      Win,Wlin,Wsrc,Wdst,Wp1,Wp2,Wa1,Wa2,Wout,
      bin,bp1,bp2,ba1,ba2,bout, Bf, FB, ei, deg, E);
  k_scanA<<<dim3(nscb), dim3(256), 0, stream>>>(deg, row_start, bsum, N);
  k_scanBC<<<dim3(nscb), dim3(256), 0, stream>>>(bsum, row_start, nscb, N);
  // scatter ∥ node ∥ zero(S,num)
  k_mid2<<<dim3(sblocks + nodeblocks + zblocks), dim3(256), 0, stream>>>(
      ei, row_start, cursor, pair, E, sblocks,
      x, Bf, FB, vfb, asb, adb, N, ntiles, nodeblocks,
      S, zcount4, zblocks);
  k_edge_p11<<<dim3(eblocks), dim3(256), 0, stream>>>(row_start, pair, pos, Bf, FB,
                                                      vfb, asb, adb, S, num, E, nsuper, spw);
  k_out_m<<<dim3((ntiles+3)/4), dim3(256), 0, stream>>>(num, S, Bf, FB, (float*)d_out, N, ntiles);
}